// Round 1
// baseline (19.998 us; speedup 1.0000x reference)
//
#include <hip/hip_runtime.h>
#include <math.h>

#define NP 16
#define TOTAL 5776
#define NB 8192
#define EPS 0.1f
#define MAXK 10   // 640 / 64

__device__ __constant__ int d_counts[NP] = {128,256,512,384,192,640,320,448,256,512,128,384,576,320,448,256};
__device__ __constant__ int d_starts[NP] = {0,128,384,896,1280,1472,2112,2432,2880,3136,3648,3776,4160,4736,5056,5504};

// One wave (64 lanes) per sample; 4 waves per block.
__global__ __launch_bounds__(256) void mlce_sample_kernel(
        const float* __restrict__ predicts,
        const int* __restrict__ parent_t,
        const int* __restrict__ child_t,
        float* __restrict__ ws)
{
    const int wave = threadIdx.x >> 6;
    const int lane = threadIdx.x & 63;
    const int b = (blockIdx.x << 2) + wave;
    if (b >= NB) return;

    const float* __restrict__ row = predicts + (size_t)b * TOTAL;
    const int p = parent_t[b];
    const int t = child_t[b];
    const int c = d_counts[p];   // multiple of 64 -> wave-uniform trip count
    const int s = d_starts[p];
    const float* __restrict__ ch = row + NP + s;

    // ---- child range: load into registers (static indices), track max ----
    float v[MAXK];
    float vmax = -INFINITY;
#pragma unroll
    for (int k = 0; k < MAXK; ++k) {
        const int j = lane + (k << 6);
        v[k] = (j < c) ? ch[j] : -INFINITY;
        vmax = fmaxf(vmax, v[k]);
    }
    // wave butterfly max (deterministic)
#pragma unroll
    for (int off = 32; off; off >>= 1) vmax = fmaxf(vmax, __shfl_xor(vmax, off));

    float se = 0.f, sx = 0.f;
#pragma unroll
    for (int k = 0; k < MAXK; ++k) {
        const int j = lane + (k << 6);
        if (j < c) { se += expf(v[k] - vmax); sx += v[k]; }
    }
#pragma unroll
    for (int off = 32; off; off >>= 1) {
        se += __shfl_xor(se, off);
        sx += __shfl_xor(sx, off);
    }

    // ---- parent softmax over 16 logits (lanes 0..15 hold data) ----
    const float pv = (lane < NP) ? row[lane] : -INFINITY;
    float pmax = pv;
#pragma unroll
    for (int off = 32; off; off >>= 1) pmax = fmaxf(pmax, __shfl_xor(pmax, off));
    float pse = (lane < NP) ? expf(pv - pmax) : 0.f;
    float psx = (lane < NP) ? pv : 0.f;
#pragma unroll
    for (int off = 32; off; off >>= 1) {
        pse += __shfl_xor(pse, off);
        psx += __shfl_xor(psx, off);
    }

    if (lane == 0) {
        // child loss: -(1-e)*lp[t] - (e/c)*sum_j lp[j]
        const float logZc = logf(se);
        const float xt = ch[t];                  // t < 128 <= c always
        const float loss_c = -(1.f - EPS) * (xt - vmax - logZc)
                             - (EPS / (float)c) * sx
                             + EPS * (vmax + logZc);
        // parent loss, same closed form with c = 16
        const float logZp = logf(pse);
        const float xpt = row[p];
        const float loss_p = -(1.f - EPS) * (xpt - pmax - logZp)
                             - (EPS / (float)NP) * psx
                             + EPS * (pmax + logZp);
        ws[b] = loss_c + loss_p;
    }
}

// Deterministic single-block reduction: out[0] = sum(ws) / NB
__global__ __launch_bounds__(256) void mlce_reduce_kernel(
        const float* __restrict__ ws, float* __restrict__ out)
{
    __shared__ float sdata[4];
    float sum = 0.f;
    for (int i = threadIdx.x; i < NB; i += 256) sum += ws[i];
#pragma unroll
    for (int off = 32; off; off >>= 1) sum += __shfl_xor(sum, off);
    const int wave = threadIdx.x >> 6;
    const int lane = threadIdx.x & 63;
    if (lane == 0) sdata[wave] = sum;
    __syncthreads();
    if (threadIdx.x == 0) {
        out[0] = (sdata[0] + sdata[1] + sdata[2] + sdata[3]) * (1.f / (float)NB);
    }
}

extern "C" void kernel_launch(void* const* d_in, const int* in_sizes, int n_in,
                              void* d_out, int out_size, void* d_ws, size_t ws_size,
                              hipStream_t stream)
{
    const float* predicts = (const float*)d_in[0];
    const int*   parent_t = (const int*)d_in[1];
    const int*   child_t  = (const int*)d_in[2];
    float* out = (float*)d_out;
    float* ws  = (float*)d_ws;

    mlce_sample_kernel<<<NB / 4, 256, 0, stream>>>(predicts, parent_t, child_t, ws);
    mlce_reduce_kernel<<<1, 256, 0, stream>>>(ws, out);
}